// Round 7
// baseline (160.933 us; speedup 1.0000x reference)
//
#include <hip/hip_runtime.h>

// ---------------------------------------------------------------------------
// GeometricSuperpositionSearch (all fp32): the reference collapses to
//   new[b,n,l] = sum_j x[b,n,j] * comb[b][j^l] * sign(j^l, j)
// with comb[b][i] = sum_k weights[b,k]*scores[b,k]*(templates[k,i]+rule_mod[b,k,i]).
//
// R7: R6 structure (k1+last-block finalizer, k3 apply), but the finalizer's
// ~200 serial global-load rounds (the real 50 us bottleneck, measured R6:
// 53 us at 0.9 GB/s = pure latency) are eliminated by staging ALL small
// arrays (~18 KB) into LDS at kernel entry with independent coalesced loads
// that hide under phase-1 streaming. Finalizer reads only LDS.
// RNG verified (R3): jax partitionable threefry, counter (0, flat), key (0,42),
// bits = y0 ^ y1.
// ---------------------------------------------------------------------------

#define B_ 8
#define N_ 65536
#define D_ 16
#define K_ 8
#define M_ 8
#define HID_ 64
#define BLK_PER_B 64                     // k1 blocks per batch (512 total)
#define ROWS_PER_BLK (N_ / BLK_PER_B)    // 1024 rows -> 4096 float4 per slab

// ---- compile-time Cayley sign table: SGN.v[a][b] = sign of e_a * e_b -> e_{a^b}
struct SgnTab { float v[16][16]; };
constexpr SgnTab make_sgn() {
  SgnTab t{};
  for (int a = 0; a < 16; a++)
    for (int b = 0; b < 16; b++) {
      float s = 1.0f;
      for (int i = 0; i < 4; i++)
        if ((b >> i) & 1) {
          int h = a >> (i + 1), pc = 0;
          for (int q = 0; q < 4; q++) pc += (h >> q) & 1;
          if (pc & 1) s = -s;
          if ((a >> i) & 1) s *= (i == 0 ? 0.0f : 1.0f);  // metric {0,1,1,1}
        }
      t.v[a][b] = s;
    }
  return t;
}
constexpr SgnTab SGN = make_sgn();

// ---- threefry2x32-20, exactly as in jax/_src/prng.py ----
__device__ __forceinline__ unsigned rotl32(unsigned x, int n) {
  return (x << n) | (x >> (32 - n));
}
__device__ void threefry2x32(unsigned k0, unsigned k1, unsigned& x0, unsigned& x1) {
  unsigned ks0 = k0, ks1 = k1, ks2 = k0 ^ k1 ^ 0x1BD11BDAu;
  x0 += ks0; x1 += ks1;
  const int rotA[4] = {13, 15, 26, 6};
  const int rotB[4] = {17, 29, 16, 24};
#define TF_R4(rot)                                      \
  _Pragma("unroll")                                     \
  for (int r = 0; r < 4; r++) {                         \
    x0 += x1; x1 = rotl32(x1, rot[r]); x1 ^= x0;        \
  }
  TF_R4(rotA); x0 += ks1; x1 += ks2 + 1u;
  TF_R4(rotB); x0 += ks2; x1 += ks0 + 2u;
  TF_R4(rotA); x0 += ks0; x1 += ks1 + 3u;
  TF_R4(rotB); x0 += ks1; x1 += ks2 + 4u;
  TF_R4(rotA); x0 += ks2; x1 += ks0 + 5u;
#undef TF_R4
}

// ---------------------------------------------------------------------------
// k1: slab partial sums + last-block finalizer computing comb[8][16].
// All small arrays staged to LDS up-front (latency hidden under phase 1).
// grid (BLK_PER_B, B_) = 512 blocks, 256 threads
// ---------------------------------------------------------------------------
__global__ __launch_bounds__(256) void k1_reduce_finalize(
    const float* __restrict__ cpu,
    const float* __restrict__ ctrl,      // [8,4]
    const float* __restrict__ rulemem,   // [8,8,16]
    const float* __restrict__ templates, // [8,16]
    const float* __restrict__ W1,        // [9,64]
    const float* __restrict__ b1,        // [64]
    const float* __restrict__ W2,        // [64,8]
    const float* __restrict__ b2,        // [8]
    const float* __restrict__ Wr,        // [16,128]
    const float* __restrict__ br,        // [128]
    const float* __restrict__ logt,     // [1]
    float* __restrict__ partial,         // ws: [8][64][16]
    unsigned* __restrict__ counter,      // ws: zeroed before launch
    float* __restrict__ comb) {          // ws: [8][16]
  const int b = blockIdx.y, blk = blockIdx.x, t = threadIdx.x;

  // ---- all shared at function scope (prevents compiler aliasing) ----
  __shared__ float red[256 * 4];
  __shared__ float sW1[9 * 64], sb1[64], sW2[64 * 8], sb2[8];
  __shared__ float sWr[16 * 128], sbr[128], stpl[8 * 16], srm[8 * 8 * 16];
  __shared__ float sctrl[32], slogt;
  __shared__ float redA[8][16][16];      // [b][seg][d]
  __shared__ float summary[8][16], rs[8][16], gn[8][5], h[8][64], sc[8][8];
  __shared__ float instr[8][8][16], g64[64], wts[8][8];
  __shared__ int isLast;

  // ===== stage small arrays into LDS: independent coalesced loads, no
  // barrier here — phase-1's __syncthreads covers them; latency hides
  // under the streaming reduce =====
  for (int i = t; i < 9 * 64; i += 256) sW1[i] = W1[i];
  for (int i = t; i < 64 * 8; i += 256) sW2[i] = W2[i];
  for (int i = t; i < 16 * 128; i += 256) sWr[i] = Wr[i];
  for (int i = t; i < 8 * 8 * 16; i += 256) srm[i] = rulemem[i];
  if (t < 64) sb1[t] = b1[t];
  if (t < 8) sb2[t] = b2[t];
  if (t < 128) sbr[t] = br[t];
  if (t < 128) stpl[t] = templates[t];
  if (t < 32) sctrl[t] = ctrl[t];
  if (t == 0) slogt = logt[0];

  // ===== phase 1: slab partial sums (verified R4 k1) =====
  {
    const float4* base =
        (const float4*)(cpu + (((size_t)b << 16) + (size_t)blk * ROWS_PER_BLK) * D_);
    float a0 = 0.f, a1 = 0.f, a2 = 0.f, a3 = 0.f;
#pragma unroll
    for (int i = 0; i < (ROWS_PER_BLK * 4) / 256; i++) {   // 16 iters
      float4 v = base[i * 256 + t];
      a0 += v.x; a1 += v.y; a2 += v.z; a3 += v.w;
    }
    red[t * 4 + 0] = a0; red[t * 4 + 1] = a1;
    red[t * 4 + 2] = a2; red[t * 4 + 3] = a3;
    __syncthreads();                      // also covers LDS staging above
    if (t < 16) {
      const int c = t >> 2, j = t & 3;    // component d = 4c + j
      float s = 0.f;
#pragma unroll
      for (int m = 0; m < 64; m++) s += red[(c + 4 * m) * 4 + j];
      partial[((size_t)b * BLK_PER_B + blk) * 16 + t] = s;
    }
  }

  // ===== last-block election (release: fence then atomic) =====
  __threadfence();                         // make partial visible device-wide
  if (t == 0) {
    unsigned old = atomicAdd(counter, 1u);
    isLast = (old == (unsigned)(B_ * BLK_PER_B - 1));
  }
  __syncthreads();
  if (!isLast) return;
  __threadfence();                         // acquire: see all partials

  // ===== finalizer: all-LDS compute (only `partial` is global: 32 loads) ====
  {
    // flat idx = c*256 + t over partial[8192]: d = t&15, seg = t>>4, b = c>>2
    float acc[8];
#pragma unroll
    for (int bb = 0; bb < 8; bb++) acc[bb] = 0.f;
#pragma unroll
    for (int c = 0; c < 32; c++)
      acc[c >> 2] += partial[c * 256 + t]; // 32 coalesced, independent loads
#pragma unroll
    for (int bb = 0; bb < 8; bb++) redA[bb][t >> 4][t & 15] = acc[bb];
  }
  __syncthreads();
  if (t < 128) {
    const int bb = t >> 4, d = t & 15;
    float s = 0.f;
#pragma unroll
    for (int g = 0; g < 16; g++) s += redA[bb][g][d];
    summary[bb][d] = s * (1.0f / (float)N_);
    float rsum = 0.f;
#pragma unroll
    for (int m = 0; m < M_; m++) rsum += srm[(bb * M_ + m) * 16 + d];
    rs[bb][d] = rsum * (1.0f / (float)M_);
  }
  __syncthreads();
  if (t < 40) {
    const int bb = t / 5, g = t % 5;
    float s = 0.f;
#pragma unroll
    for (int d = 0; d < 16; d++)
      if (__popc(d) == g) { float v = summary[bb][d]; s += v * v; }
    gn[bb][g] = sqrtf(s + 1e-12f);
  }
  __syncthreads();
#pragma unroll
  for (int rep = 0; rep < 2; rep++) {      // B_*HID_ = 512 = 2*256
    const int idx = rep * 256 + t;
    const int bb = idx >> 6, j = idx & 63;
    float a = sb1[j];
#pragma unroll
    for (int i = 0; i < 9; i++) {
      float in = (i < 5) ? gn[bb][i] : sctrl[bb * 4 + (i - 5)];
      a += in * sW1[i * HID_ + j];
    }
    h[bb][j] = fmaxf(a, 0.f);
  }
  __syncthreads();
  if (t < 64) {
    const int bb = t >> 3, k = t & 7;
    float a = sb2[k];
#pragma unroll
    for (int j = 0; j < HID_; j++) a += h[bb][j] * sW2[j * K_ + k];
    sc[bb][k] = a;
  }
  __syncthreads();
#pragma unroll
  for (int rep = 0; rep < 4; rep++) {      // B_*K_*16 = 1024 = 4*256
    const int idx = rep * 256 + t;
    const int bb = idx >> 7, k = (idx >> 4) & 7, d = idx & 15;
    float a = sbr[k * 16 + d];
#pragma unroll
    for (int j = 0; j < 16; j++) a += rs[bb][j] * sWr[j * 128 + k * 16 + d];
    instr[bb][k][d] = sc[bb][k] * (stpl[k * 16 + d] + a);
  }
  // gumbel: jax partitionable threefry over shape (8,8): counter (0,t), key (0,42)
  if (t < 64) {
    unsigned x0 = 0u, x1 = (unsigned)t;
    threefry2x32(0u, 42u, x0, x1);
    unsigned bits = x0 ^ x1;
    float f01 = __uint_as_float((bits >> 9) | 0x3f800000u) - 1.0f;
    float u = fmaxf(1e-6f, f01 * (1.0f - 2e-6f) + 1e-6f);
    g64[t] = -logf(-logf(u));
  }
  __syncthreads();
  if (t < 8) {
    float tau = fminf(fmaxf(expf(slogt), 0.1f), 5.0f);
    float z[8], m = -1e30f;
#pragma unroll
    for (int k = 0; k < 8; k++) {
      z[k] = (sc[t][k] + g64[t * 8 + k]) / tau;
      m = fmaxf(m, z[k]);
    }
    float ssum = 0.f;
#pragma unroll
    for (int k = 0; k < 8; k++) { z[k] = expf(z[k] - m); ssum += z[k]; }
#pragma unroll
    for (int k = 0; k < 8; k++) wts[t][k] = z[k] / ssum;
  }
  __syncthreads();
  if (t < 128) {
    const int bb = t >> 4, i = t & 15;
    float s = 0.f;
#pragma unroll
    for (int k = 0; k < 8; k++) s += wts[bb][k] * instr[bb][k][i];
    comb[bb * 16 + i] = s;
  }
  // kernel-boundary flush makes comb visible to k3 (stream-ordered)
}

// ---------------------------------------------------------------------------
// k3: out[b,n,l] = sum_j x[b,n,j] * comb[b][j^l] * SGN[j^l][j]
// grid 2048 blocks x 256 threads, 1 row/thread (verified R4)
// ---------------------------------------------------------------------------
__global__ __launch_bounds__(256) void k3_apply(
    const float* __restrict__ cpu, const float* __restrict__ comb,
    float* __restrict__ out) {
  const int b = blockIdx.x >> 8;                       // wave-uniform
  const int rowInB = ((blockIdx.x & 255) << 8) + threadIdx.x;
  const size_t row = ((size_t)b << 16) + (size_t)rowInB;

  float cb[16];
  const float* cp = comb + b * 16;
#pragma unroll
  for (int i = 0; i < 16; i++) cb[i] = cp[i];          // uniform -> s_load

  const float4* p = (const float4*)(cpu + row * D_);
  float4 v0 = p[0], v1 = p[1], v2 = p[2], v3 = p[3];
  float x[16] = {v0.x, v0.y, v0.z, v0.w, v1.x, v1.y, v1.z, v1.w,
                 v2.x, v2.y, v2.z, v2.w, v3.x, v3.y, v3.z, v3.w};

  float o[16];
#pragma unroll
  for (int l = 0; l < 16; l++) {
    float acc = 0.f;
#pragma unroll
    for (int j = 0; j < 16; j++) {
      const float s = SGN.v[j ^ l][j];                 // compile-time constant
      if (s > 0.5f)       acc = fmaf(cb[j ^ l], x[j], acc);
      else if (s < -0.5f) acc = fmaf(-cb[j ^ l], x[j], acc);
    }
    o[l] = acc;
  }

  float4* q = (float4*)(out + row * D_);
  q[0] = make_float4(o[0],  o[1],  o[2],  o[3]);
  q[1] = make_float4(o[4],  o[5],  o[6],  o[7]);
  q[2] = make_float4(o[8],  o[9],  o[10], o[11]);
  q[3] = make_float4(o[12], o[13], o[14], o[15]);
}

extern "C" void kernel_launch(void* const* d_in, const int* in_sizes, int n_in,
                              void* d_out, int out_size, void* d_ws, size_t ws_size,
                              hipStream_t stream) {
  const float* cpu       = (const float*)d_in[0];
  const float* ctrl      = (const float*)d_in[1];
  const float* rulemem   = (const float*)d_in[2];
  const float* templates = (const float*)d_in[3];
  const float* W1        = (const float*)d_in[4];
  const float* b1        = (const float*)d_in[5];
  const float* W2        = (const float*)d_in[6];
  const float* b2        = (const float*)d_in[7];
  const float* Wr        = (const float*)d_in[8];
  const float* br        = (const float*)d_in[9];
  const float* logt      = (const float*)d_in[10];

  float*    partial = (float*)d_ws;                           // 8192 floats
  unsigned* counter = (unsigned*)(partial + 8192);            // 1 u32 (64B slot)
  float*    comb    = (float*)((char*)(void*)counter + 64);   // 128 floats

  hipMemsetAsync(counter, 0, 64, stream);
  k1_reduce_finalize<<<dim3(BLK_PER_B, B_), 256, 0, stream>>>(
      cpu, ctrl, rulemem, templates, W1, b1, W2, b2, Wr, br, logt,
      partial, counter, comb);
  k3_apply<<<2048, 256, 0, stream>>>(cpu, comb, (float*)d_out);
}

// Round 8
// 122.834 us; speedup vs baseline: 1.3102x; 1.3102x over previous
//
#include <hip/hip_runtime.h>

// ---------------------------------------------------------------------------
// GeometricSuperpositionSearch (all fp32): the reference collapses to
//   new[b,n,l] = sum_j x[b,n,j] * comb[b][j^l] * sign(j^l, j)
// with comb[b][i] = sum_k weights[b,k]*scores[b,k]*(templates[k,i]+rule_mod[b,k,i]).
//
// R8: TWO plain kernels (R6/R7 atomic+threadfence finalizer was ~40 us WORSE
// than plain kernels; k1's streaming read is drain-limited ~260 GB/s, not
// fixable in-kernel).
//  k1: 512 blocks reduce slabs -> partial  (verified R4 k1, unchanged)
//  k3: 2048 blocks; each block REDUNDANTLY computes comb for its batch from
//      partial + LDS-staged small arrays (deterministic per batch), then
//      applies the operator to its 256 rows (verified R4 apply body).
// RNG verified (R3): jax partitionable threefry, counter (0, flat), key (0,42),
// bits = y0 ^ y1.
// ---------------------------------------------------------------------------

#define B_ 8
#define N_ 65536
#define D_ 16
#define K_ 8
#define M_ 8
#define HID_ 64
#define BLK_PER_B 64                     // k1 blocks per batch (512 total)
#define ROWS_PER_BLK (N_ / BLK_PER_B)    // 1024 rows -> 4096 float4 per slab

// ---- compile-time Cayley sign table: SGN.v[a][b] = sign of e_a * e_b -> e_{a^b}
struct SgnTab { float v[16][16]; };
constexpr SgnTab make_sgn() {
  SgnTab t{};
  for (int a = 0; a < 16; a++)
    for (int b = 0; b < 16; b++) {
      float s = 1.0f;
      for (int i = 0; i < 4; i++)
        if ((b >> i) & 1) {
          int h = a >> (i + 1), pc = 0;
          for (int q = 0; q < 4; q++) pc += (h >> q) & 1;
          if (pc & 1) s = -s;
          if ((a >> i) & 1) s *= (i == 0 ? 0.0f : 1.0f);  // metric {0,1,1,1}
        }
      t.v[a][b] = s;
    }
  return t;
}
constexpr SgnTab SGN = make_sgn();

// ---- threefry2x32-20, exactly as in jax/_src/prng.py ----
__device__ __forceinline__ unsigned rotl32(unsigned x, int n) {
  return (x << n) | (x >> (32 - n));
}
__device__ void threefry2x32(unsigned k0, unsigned k1, unsigned& x0, unsigned& x1) {
  unsigned ks0 = k0, ks1 = k1, ks2 = k0 ^ k1 ^ 0x1BD11BDAu;
  x0 += ks0; x1 += ks1;
  const int rotA[4] = {13, 15, 26, 6};
  const int rotB[4] = {17, 29, 16, 24};
#define TF_R4(rot)                                      \
  _Pragma("unroll")                                     \
  for (int r = 0; r < 4; r++) {                         \
    x0 += x1; x1 = rotl32(x1, rot[r]); x1 ^= x0;        \
  }
  TF_R4(rotA); x0 += ks1; x1 += ks2 + 1u;
  TF_R4(rotB); x0 += ks2; x1 += ks0 + 2u;
  TF_R4(rotA); x0 += ks0; x1 += ks1 + 3u;
  TF_R4(rotB); x0 += ks1; x1 += ks2 + 4u;
  TF_R4(rotA); x0 += ks2; x1 += ks0 + 5u;
#undef TF_R4
}

// ---------------------------------------------------------------------------
// k1: per-(b,d) partial sums of cpu_state over a 1024-row slab (verified R4).
// grid (BLK_PER_B, B_), 256 threads
// ---------------------------------------------------------------------------
__global__ __launch_bounds__(256) void k1_reduce(
    const float* __restrict__ cpu, float* __restrict__ partial) {
  const int b = blockIdx.y, blk = blockIdx.x, t = threadIdx.x;
  const float4* base =
      (const float4*)(cpu + (((size_t)b << 16) + (size_t)blk * ROWS_PER_BLK) * D_);
  float a0 = 0.f, a1 = 0.f, a2 = 0.f, a3 = 0.f;
#pragma unroll
  for (int i = 0; i < (ROWS_PER_BLK * 4) / 256; i++) {   // 16 iters
    float4 v = base[i * 256 + t];
    a0 += v.x; a1 += v.y; a2 += v.z; a3 += v.w;
  }
  __shared__ float red[256 * 4];
  red[t * 4 + 0] = a0; red[t * 4 + 1] = a1;
  red[t * 4 + 2] = a2; red[t * 4 + 3] = a3;
  __syncthreads();
  if (t < 16) {
    const int c = t >> 2, j = t & 3;      // component d = 4c + j
    float s = 0.f;
#pragma unroll
    for (int m = 0; m < 64; m++) s += red[(c + 4 * m) * 4 + j];
    partial[((size_t)b * BLK_PER_B + blk) * 16 + t] = s;
  }
}

// ---------------------------------------------------------------------------
// k3: per-block redundant comb computation + apply.
// grid 2048 blocks x 256 threads, 1 row/thread.
// ---------------------------------------------------------------------------
__global__ __launch_bounds__(256) void k3_comb_apply(
    const float* __restrict__ cpu,
    const float* __restrict__ partial,   // [8][64][16]
    const float* __restrict__ ctrl,      // [8,4]
    const float* __restrict__ rulemem,   // [8,8,16]
    const float* __restrict__ templates, // [8,16]
    const float* __restrict__ W1,        // [9,64]
    const float* __restrict__ b1,        // [64]
    const float* __restrict__ W2,        // [64,8]
    const float* __restrict__ b2,        // [8]
    const float* __restrict__ Wr,        // [16,128]
    const float* __restrict__ br,        // [128]
    const float* __restrict__ logt,      // [1]
    float* __restrict__ out) {
  const int t = threadIdx.x;
  const int b = blockIdx.x >> 8;                       // batch (wave-uniform)
  const int rowInB = ((blockIdx.x & 255) << 8) + t;
  const size_t row = ((size_t)b << 16) + (size_t)rowInB;

  // ---- LDS (function scope) ----
  __shared__ float sW1[9 * 64], sb1[64], sW2[64 * 8], sb2[8];
  __shared__ float sWr[16 * 128], sbr[128], stpl[128];
  __shared__ float srm_b[128], sctrl_b[4], slogt;
  __shared__ float red2[256 * 4];
  __shared__ float summary[16], rs[16], gn[5], h[HID_], sc[8];
  __shared__ float instr[8][16], g8[8], wts[8], comb_s[16];

  // ===== stage small arrays + this batch's partials: independent coalesced
  // loads, all before the first barrier =====
  {
    // partial[b]: 1024 floats as 256 float4 -> thread t owns comps 4*(t&3)..+3
    float4 pp = ((const float4*)(partial + (size_t)b * 1024))[t];
    for (int i = t; i < 9 * 64; i += 256) sW1[i] = W1[i];
    for (int i = t; i < 64 * 8; i += 256) sW2[i] = W2[i];
    for (int i = t; i < 16 * 128; i += 256) sWr[i] = Wr[i];
    if (t < 64) sb1[t] = b1[t];
    if (t < 8) sb2[t] = b2[t];
    if (t < 128) sbr[t] = br[t];
    if (t < 128) stpl[t] = templates[t];
    if (t < 128) srm_b[t] = rulemem[b * 128 + t];
    if (t < 4) sctrl_b[t] = ctrl[b * 4 + t];
    if (t == 0) slogt = logt[0];
    red2[t * 4 + 0] = pp.x; red2[t * 4 + 1] = pp.y;
    red2[t * 4 + 2] = pp.z; red2[t * 4 + 3] = pp.w;
  }
  __syncthreads();
  // summary tree (identical idiom to k1; deterministic per batch)
  if (t < 16) {
    const int c = t >> 2, j = t & 3;                   // component d = 4c + j
    float s = 0.f;
#pragma unroll
    for (int m = 0; m < 64; m++) s += red2[(c + 4 * m) * 4 + j];
    summary[t] = s * (1.0f / (float)N_);
    float rsum = 0.f;
#pragma unroll
    for (int m = 0; m < M_; m++) rsum += srm_b[m * 16 + t];
    rs[t] = rsum * (1.0f / (float)M_);
  }
  __syncthreads();
  if (t < 5) {
    float s = 0.f;
#pragma unroll
    for (int d = 0; d < 16; d++)
      if (__popc(d) == t) { float v = summary[d]; s += v * v; }
    gn[t] = sqrtf(s + 1e-12f);
  }
  __syncthreads();
  if (t < HID_) {
    float a = sb1[t];
#pragma unroll
    for (int i = 0; i < 9; i++) {
      float in = (i < 5) ? gn[i] : sctrl_b[i - 5];
      a += in * sW1[i * HID_ + t];
    }
    h[t] = fmaxf(a, 0.f);
  }
  __syncthreads();
  if (t < 8) {
    float a = sb2[t];
#pragma unroll
    for (int j = 0; j < HID_; j++) a += h[j] * sW2[j * K_ + t];
    sc[t] = a;
    // gumbel: jax partitionable threefry, flat index b*8+t over shape (8,8)
    unsigned x0 = 0u, x1 = (unsigned)(b * 8 + t);
    threefry2x32(0u, 42u, x0, x1);
    unsigned bits = x0 ^ x1;
    float f01 = __uint_as_float((bits >> 9) | 0x3f800000u) - 1.0f;
    float u = fmaxf(1e-6f, f01 * (1.0f - 2e-6f) + 1e-6f);
    g8[t] = -logf(-logf(u));
  }
  __syncthreads();
  if (t < 128) {
    const int k = t >> 4, d = t & 15;
    float a = sbr[k * 16 + d];
#pragma unroll
    for (int j = 0; j < 16; j++) a += rs[j] * sWr[j * 128 + k * 16 + d];
    instr[k][d] = sc[k] * (stpl[k * 16 + d] + a);
  }
  if (t == 0) {
    float tau = fminf(fmaxf(expf(slogt), 0.1f), 5.0f);
    float z[8], m = -1e30f;
#pragma unroll
    for (int k = 0; k < 8; k++) {
      z[k] = (sc[k] + g8[k]) / tau;
      m = fmaxf(m, z[k]);
    }
    float ssum = 0.f;
#pragma unroll
    for (int k = 0; k < 8; k++) { z[k] = expf(z[k] - m); ssum += z[k]; }
#pragma unroll
    for (int k = 0; k < 8; k++) wts[k] = z[k] / ssum;
  }
  __syncthreads();
  if (t < 16) {
    float s = 0.f;
#pragma unroll
    for (int k = 0; k < 8; k++) s += wts[k] * instr[k][t];
    comb_s[t] = s;
  }
  __syncthreads();

  // ===== apply (verified R4 k3 body) =====
  float cb[16];
#pragma unroll
  for (int i = 0; i < 16; i++) cb[i] = comb_s[i];

  const float4* p = (const float4*)(cpu + row * D_);
  float4 v0 = p[0], v1 = p[1], v2 = p[2], v3 = p[3];
  float x[16] = {v0.x, v0.y, v0.z, v0.w, v1.x, v1.y, v1.z, v1.w,
                 v2.x, v2.y, v2.z, v2.w, v3.x, v3.y, v3.z, v3.w};

  float o[16];
#pragma unroll
  for (int l = 0; l < 16; l++) {
    float acc = 0.f;
#pragma unroll
    for (int j = 0; j < 16; j++) {
      const float s = SGN.v[j ^ l][j];                 // compile-time constant
      if (s > 0.5f)       acc = fmaf(cb[j ^ l], x[j], acc);
      else if (s < -0.5f) acc = fmaf(-cb[j ^ l], x[j], acc);
    }
    o[l] = acc;
  }

  float4* q = (float4*)(out + row * D_);
  q[0] = make_float4(o[0],  o[1],  o[2],  o[3]);
  q[1] = make_float4(o[4],  o[5],  o[6],  o[7]);
  q[2] = make_float4(o[8],  o[9],  o[10], o[11]);
  q[3] = make_float4(o[12], o[13], o[14], o[15]);
}

extern "C" void kernel_launch(void* const* d_in, const int* in_sizes, int n_in,
                              void* d_out, int out_size, void* d_ws, size_t ws_size,
                              hipStream_t stream) {
  const float* cpu       = (const float*)d_in[0];
  const float* ctrl      = (const float*)d_in[1];
  const float* rulemem   = (const float*)d_in[2];
  const float* templates = (const float*)d_in[3];
  const float* W1        = (const float*)d_in[4];
  const float* b1        = (const float*)d_in[5];
  const float* W2        = (const float*)d_in[6];
  const float* b2        = (const float*)d_in[7];
  const float* Wr        = (const float*)d_in[8];
  const float* br        = (const float*)d_in[9];
  const float* logt      = (const float*)d_in[10];

  float* partial = (float*)d_ws;                       // 8*64*16 = 8192 floats

  k1_reduce<<<dim3(BLK_PER_B, B_), 256, 0, stream>>>(cpu, partial);
  k3_comb_apply<<<2048, 256, 0, stream>>>(cpu, partial, ctrl, rulemem,
                                          templates, W1, b1, W2, b2, Wr, br,
                                          logt, (float*)d_out);
}

// Round 9
// 121.568 us; speedup vs baseline: 1.3238x; 1.0104x over previous
//
#include <hip/hip_runtime.h>

// ---------------------------------------------------------------------------
// GeometricSuperpositionSearch (all fp32): the reference collapses to
//   new[b,n,l] = sum_j x[b,n,j] * comb[b][j^l] * sign(j^l, j)
// with comb[b][i] = sum_k weights[b,k]*scores[b,k]*(templates[k,i]+rule_mod[b,k,i]).
//
// R9: back to the verified R4 3-kernel structure (best measured: 117.6 us;
// R6/R7 atomic-finalizer and R8 redundant-comb were all slower). Single
// change: k1 at 2048 blocks (8/CU) for max memory-level parallelism while
// the harness's ~300 MB poison writes drain (k1's read measured at only
// ~260-310 GB/s in that window). k2 phase-A adapted to the 4x partial.
// RNG verified (R3): jax partitionable threefry, counter (0, flat), key (0,42),
// bits = y0 ^ y1.
// ---------------------------------------------------------------------------

#define B_ 8
#define N_ 65536
#define D_ 16
#define K_ 8
#define M_ 8
#define HID_ 64
#define BLK_PER_B 256                    // k1 blocks per batch (2048 total)
#define ROWS_PER_BLK (N_ / BLK_PER_B)    // 256 rows -> 1024 float4 per slab

// ---- compile-time Cayley sign table: SGN.v[a][b] = sign of e_a * e_b -> e_{a^b}
struct SgnTab { float v[16][16]; };
constexpr SgnTab make_sgn() {
  SgnTab t{};
  for (int a = 0; a < 16; a++)
    for (int b = 0; b < 16; b++) {
      float s = 1.0f;
      for (int i = 0; i < 4; i++)
        if ((b >> i) & 1) {
          int h = a >> (i + 1), pc = 0;
          for (int q = 0; q < 4; q++) pc += (h >> q) & 1;
          if (pc & 1) s = -s;
          if ((a >> i) & 1) s *= (i == 0 ? 0.0f : 1.0f);  // metric {0,1,1,1}
        }
      t.v[a][b] = s;
    }
  return t;
}
constexpr SgnTab SGN = make_sgn();

// ---- threefry2x32-20, exactly as in jax/_src/prng.py ----
__device__ __forceinline__ unsigned rotl32(unsigned x, int n) {
  return (x << n) | (x >> (32 - n));
}
__device__ void threefry2x32(unsigned k0, unsigned k1, unsigned& x0, unsigned& x1) {
  unsigned ks0 = k0, ks1 = k1, ks2 = k0 ^ k1 ^ 0x1BD11BDAu;
  x0 += ks0; x1 += ks1;
  const int rotA[4] = {13, 15, 26, 6};
  const int rotB[4] = {17, 29, 16, 24};
#define TF_R4(rot)                                      \
  _Pragma("unroll")                                     \
  for (int r = 0; r < 4; r++) {                         \
    x0 += x1; x1 = rotl32(x1, rot[r]); x1 ^= x0;        \
  }
  TF_R4(rotA); x0 += ks1; x1 += ks2 + 1u;
  TF_R4(rotB); x0 += ks2; x1 += ks0 + 2u;
  TF_R4(rotA); x0 += ks0; x1 += ks1 + 3u;
  TF_R4(rotB); x0 += ks1; x1 += ks2 + 4u;
  TF_R4(rotA); x0 += ks2; x1 += ks0 + 5u;
#undef TF_R4
}

// ---------------------------------------------------------------------------
// k1: per-(b,d) partial sums of cpu_state over a 256-row slab.
// grid (BLK_PER_B, B_) = 2048 blocks, 256 threads; thread t owns comp group
// 4*(t&3)..+3 (f&3 == t&3 for all its float4 indices f).
// ---------------------------------------------------------------------------
__global__ __launch_bounds__(256) void k1_reduce(
    const float* __restrict__ cpu, float* __restrict__ partial) {
  const int b = blockIdx.y, blk = blockIdx.x, t = threadIdx.x;
  const float4* base =
      (const float4*)(cpu + (((size_t)b << 16) + (size_t)blk * ROWS_PER_BLK) * D_);
  float a0 = 0.f, a1 = 0.f, a2 = 0.f, a3 = 0.f;
#pragma unroll
  for (int i = 0; i < (ROWS_PER_BLK * 4) / 256; i++) {   // 4 iters
    float4 v = base[i * 256 + t];
    a0 += v.x; a1 += v.y; a2 += v.z; a3 += v.w;
  }
  __shared__ float red[256 * 4];
  red[t * 4 + 0] = a0; red[t * 4 + 1] = a1;
  red[t * 4 + 2] = a2; red[t * 4 + 3] = a3;
  __syncthreads();
  if (t < 16) {
    const int c = t >> 2, j = t & 3;      // component d = 4c + j == t
    float s = 0.f;
#pragma unroll
    for (int m = 0; m < 64; m++) s += red[(c + 4 * m) * 4 + j];
    partial[((size_t)b * BLK_PER_B + blk) * 16 + t] = s;
  }
}

// ---------------------------------------------------------------------------
// k2: single block -> comb[8][16] (fp32). Phase A reads partial[32768] as
// 8192 float4 in 32 coalesced rounds; per-batch LDS tree mirrors k1's.
// ---------------------------------------------------------------------------
__global__ __launch_bounds__(256) void k2_small(
    const float* __restrict__ partial,   // [8][256][16] = 32768 floats
    const float* __restrict__ ctrl,      // [8,4]
    const float* __restrict__ rulemem,   // [8,8,16]
    const float* __restrict__ templates, // [8,16]
    const float* __restrict__ W1,        // [9,64]
    const float* __restrict__ b1,        // [64]
    const float* __restrict__ W2,        // [64,8]
    const float* __restrict__ b2,        // [8]
    const float* __restrict__ Wr,        // [16,128]
    const float* __restrict__ br,        // [128]
    const float* __restrict__ logt,     // [1]
    float* __restrict__ comb) {
  const int t = threadIdx.x;
  __shared__ float redA[8][256][4];      // 32 KB: [b][thread][q]
  __shared__ float summary[8][16], rs[8][16], gn[8][5], h[8][64], sc[8][8];
  __shared__ float instr[8][8][16], g64[64], wts[8][8];

  // A: cooperative float4 load+reduce.
  // F = c*256 + t (f4 index over 8192): batch = F>>10 == c>>2 (exact, t<256);
  // within-batch f4 idx G = (c&3)*256+t has G&3 == t&3 -> comp group t&3.
  {
    const float4* p4 = (const float4*)partial;
    float4 acc[8];
#pragma unroll
    for (int bb = 0; bb < 8; bb++) acc[bb] = make_float4(0.f, 0.f, 0.f, 0.f);
#pragma unroll
    for (int c = 0; c < 32; c++) {
      float4 v = p4[c * 256 + t];        // 32 coalesced, independent loads
      acc[c >> 2].x += v.x; acc[c >> 2].y += v.y;
      acc[c >> 2].z += v.z; acc[c >> 2].w += v.w;
    }
#pragma unroll
    for (int bb = 0; bb < 8; bb++) {
      redA[bb][t][0] = acc[bb].x; redA[bb][t][1] = acc[bb].y;
      redA[bb][t][2] = acc[bb].z; redA[bb][t][3] = acc[bb].w;
    }
  }
  __syncthreads();
  if (t < 128) {
    const int bb = t >> 4, d = t & 15;
    const int c = d >> 2, j = d & 3;     // threads m with m&3==c hold comp d
    float s = 0.f;
#pragma unroll
    for (int m = 0; m < 64; m++) s += redA[bb][c + 4 * m][j];
    summary[bb][d] = s * (1.0f / (float)N_);
    float rsum = 0.f;
#pragma unroll
    for (int m = 0; m < M_; m++) rsum += rulemem[(bb * M_ + m) * 16 + d];
    rs[bb][d] = rsum * (1.0f / (float)M_);
  }
  __syncthreads();
  // B: grade norms
  if (t < 40) {
    const int bb = t / 5, g = t % 5;
    float s = 0.f;
    for (int d = 0; d < 16; d++)
      if (__popc(d) == g) { float v = summary[bb][d]; s += v * v; }
    gn[bb][g] = sqrtf(s + 1e-12f);
  }
  __syncthreads();
  // C1: hidden layer [8][64]
  for (int idx = t; idx < B_ * HID_; idx += 256) {
    const int bb = idx >> 6, j = idx & 63;
    float a = b1[j];
    for (int i = 0; i < 9; i++) {
      float in = (i < 5) ? gn[bb][i] : ctrl[bb * 4 + (i - 5)];
      a += in * W1[i * HID_ + j];
    }
    h[bb][j] = fmaxf(a, 0.f);
  }
  __syncthreads();
  // C2: scores [8][8]
  if (t < 64) {
    const int bb = t >> 3, k = t & 7;
    float a = b2[k];
    for (int j = 0; j < HID_; j++) a += h[bb][j] * W2[j * K_ + k];
    sc[bb][k] = a;
  }
  __syncthreads();
  // D: instructions [8][8][16] = scores * (templates + rule_mod)
  for (int idx = t; idx < B_ * K_ * 16; idx += 256) {
    const int bb = idx >> 7, k = (idx >> 4) & 7, d = idx & 15;
    float a = br[k * 16 + d];
    for (int j = 0; j < 16; j++) a += rs[bb][j] * Wr[j * 128 + k * 16 + d];
    instr[bb][k][d] = sc[bb][k] * (templates[k * 16 + d] + a);
  }
  // E: gumbel — jax partitionable threefry: counter (0, t), key (0, 42)
  if (t < 64) {
    unsigned x0 = 0u, x1 = (unsigned)t;
    threefry2x32(0u, 42u, x0, x1);
    unsigned bits = x0 ^ x1;
    float f01 = __uint_as_float((bits >> 9) | 0x3f800000u) - 1.0f;
    float u = fmaxf(1e-6f, f01 * (1.0f - 2e-6f) + 1e-6f);
    g64[t] = -logf(-logf(u));
  }
  __syncthreads();
  // weights: softmax((scores+g)/tau)
  if (t < 8) {
    float lt = logt[0];
    float tau = fminf(fmaxf(expf(lt), 0.1f), 5.0f);
    float z[8], m = -1e30f;
    for (int k = 0; k < 8; k++) {
      z[k] = (sc[t][k] + g64[t * 8 + k]) / tau;
      m = fmaxf(m, z[k]);
    }
    float ssum = 0.f;
    for (int k = 0; k < 8; k++) { z[k] = expf(z[k] - m); ssum += z[k]; }
    for (int k = 0; k < 8; k++) wts[t][k] = z[k] / ssum;
  }
  __syncthreads();
  // F: comb[b][i] = sum_k w * instr
  if (t < 128) {
    const int bb = t >> 4, i = t & 15;
    float s = 0.f;
    for (int k = 0; k < 8; k++) s += wts[bb][k] * instr[bb][k][i];
    comb[bb * 16 + i] = s;
  }
}

// ---------------------------------------------------------------------------
// k3: out[b,n,l] = sum_j x[b,n,j] * comb[b][j^l] * SGN[j^l][j]
// grid 2048 blocks x 256 threads, 1 row/thread (verified R4)
// ---------------------------------------------------------------------------
__global__ __launch_bounds__(256) void k3_apply(
    const float* __restrict__ cpu, const float* __restrict__ comb,
    float* __restrict__ out) {
  const int b = blockIdx.x >> 8;                       // wave-uniform
  const int rowInB = ((blockIdx.x & 255) << 8) + threadIdx.x;
  const size_t row = ((size_t)b << 16) + (size_t)rowInB;

  float cb[16];
  const float* cp = comb + b * 16;
#pragma unroll
  for (int i = 0; i < 16; i++) cb[i] = cp[i];          // uniform -> s_load

  const float4* p = (const float4*)(cpu + row * D_);
  float4 v0 = p[0], v1 = p[1], v2 = p[2], v3 = p[3];
  float x[16] = {v0.x, v0.y, v0.z, v0.w, v1.x, v1.y, v1.z, v1.w,
                 v2.x, v2.y, v2.z, v2.w, v3.x, v3.y, v3.z, v3.w};

  float o[16];
#pragma unroll
  for (int l = 0; l < 16; l++) {
    float acc = 0.f;
#pragma unroll
    for (int j = 0; j < 16; j++) {
      const float s = SGN.v[j ^ l][j];                 // compile-time constant
      if (s > 0.5f)       acc = fmaf(cb[j ^ l], x[j], acc);
      else if (s < -0.5f) acc = fmaf(-cb[j ^ l], x[j], acc);
    }
    o[l] = acc;
  }

  float4* q = (float4*)(out + row * D_);
  q[0] = make_float4(o[0],  o[1],  o[2],  o[3]);
  q[1] = make_float4(o[4],  o[5],  o[6],  o[7]);
  q[2] = make_float4(o[8],  o[9],  o[10], o[11]);
  q[3] = make_float4(o[12], o[13], o[14], o[15]);
}

extern "C" void kernel_launch(void* const* d_in, const int* in_sizes, int n_in,
                              void* d_out, int out_size, void* d_ws, size_t ws_size,
                              hipStream_t stream) {
  const float* cpu       = (const float*)d_in[0];
  const float* ctrl      = (const float*)d_in[1];
  const float* rulemem   = (const float*)d_in[2];
  const float* templates = (const float*)d_in[3];
  const float* W1        = (const float*)d_in[4];
  const float* b1        = (const float*)d_in[5];
  const float* W2        = (const float*)d_in[6];
  const float* b2        = (const float*)d_in[7];
  const float* Wr        = (const float*)d_in[8];
  const float* br        = (const float*)d_in[9];
  const float* logt      = (const float*)d_in[10];

  float* partial = (float*)d_ws;                           // 8*256*16 floats
  float* comb    = partial + (size_t)B_ * BLK_PER_B * 16;  // 128 floats

  k1_reduce<<<dim3(BLK_PER_B, B_), 256, 0, stream>>>(cpu, partial);
  k2_small<<<1, 256, 0, stream>>>(partial, ctrl, rulemem, templates, W1, b1,
                                  W2, b2, Wr, br, logt, comb);
  k3_apply<<<2048, 256, 0, stream>>>(cpu, comb, (float*)d_out);
}